// Round 13
// baseline (116.014 us; speedup 1.0000x reference)
//
#include <hip/hip_runtime.h>
#include <math.h>

#define NN 768
#define CC 256
#define TI 3     // rows per k_prep block (row-triple)
#define RT 6     // rows per k_attn block (2 triples)
#define JC 128   // j columns per k_attn block
#define NJC 6    // j chunks: 6 * 128 = 768

__device__ __forceinline__ float leaky(float x) { return x >= 0.0f ? x : 0.2f * x; }

__device__ __forceinline__ float rl(float v, int l) {   // wave broadcast, VALU pipe
    return __uint_as_float(__builtin_amdgcn_readlane(__float_as_uint(v), l));
}

__device__ __forceinline__ float waveMax(float v) {
    #pragma unroll
    for (int o = 32; o > 0; o >>= 1) v = fmaxf(v, __shfl_xor(v, o, 64));
    return v;
}
__device__ __forceinline__ float waveSum(float v) {
    #pragma unroll
    for (int o = 32; o > 0; o >>= 1) v += __shfl_xor(v, o, 64);
    return v;
}

__device__ __forceinline__ void fma4(float4& h, float e, const float4& fv) {
    h.x = fmaf(e, fv.x, h.x);
    h.y = fmaf(e, fv.y, h.y);
    h.z = fmaf(e, fv.z, h.z);
    h.w = fmaf(e, fv.w, h.w);
}

// Kernel 1 (unchanged): f = features @ FC; g[c][j] = w1*f[j][c]+b;
// D0/D1 = per-row linear-term dots; ut4[triple][c] = {w0*f_r0[c], w0*f_r1[c],
// w0*f_r2[c], 0.4*lin_w[c]}.
__global__ __launch_bounds__(768) void k_prep(
    const float* __restrict__ features,
    const float* __restrict__ FC,
    const float* __restrict__ fc_w,
    const float* __restrict__ fc_b,
    const float* __restrict__ lin_w,
    float* __restrict__ f,
    float* __restrict__ g,
    float* __restrict__ D0,
    float* __restrict__ D1,
    float4* __restrict__ ut4)
{
    __shared__ float sA[TI * CC];
    __shared__ float sF[TI * CC];
    __shared__ float sredD[12], sredW[12];

    const int t  = threadIdx.x;
    const int r  = t >> 8;
    const int c  = t & 255;
    const int i0 = blockIdx.x * TI;

    sA[r * CC + c] = features[(i0 + r) * CC + c];
    __syncthreads();

    float a = 0.f;
    const float* fcp = FC + c;
    const float* ap  = sA + r * CC;
    #pragma unroll 8
    for (int k = 0; k < CC; ++k)
        a = fmaf(ap[k], fcp[k * CC], a);

    const float w1 = fc_w[1], b = fc_b[0];
    f[(i0 + r) * CC + c] = a;
    g[c * NN + i0 + r]   = fmaf(w1, a, b);
    sF[r * CC + c] = a;

    const float lw = lin_w[c];
    float dv = waveSum(lw * a);
    float wv = waveSum(lw);
    const int wid = t >> 6;
    if ((t & 63) == 0) { sredD[wid] = dv; sredW[wid] = wv; }
    __syncthreads();
    if (t < TI) {
        float D = sredD[t*4] + sredD[t*4+1] + sredD[t*4+2] + sredD[t*4+3];
        float W = sredW[t*4] + sredW[t*4+1] + sredW[t*4+2] + sredW[t*4+3];
        D0[i0 + t] = fc_w[0] * D;
        D1[i0 + t] = fmaf(w1, D, b * W);
    }
    if (t < CC) {
        const float w0 = fc_w[0];
        ut4[blockIdx.x * CC + t] = make_float4(w0 * sF[t],
                                               w0 * sF[CC + t],
                                               w0 * sF[2*CC + t],
                                               0.4f * lin_w[t]);
    }
}

// Kernel 2: 768 blocks (128 row-tiles of 6 x 6 j-chunks of 128) x 256 threads
// = 3 blocks/CU, 12 waves. RT=6 halves the per-CU g/f TCP traffic vs RT=3
// (1.5 MB -> 768 KB: the ~11 us VMEM term that capped rounds 7-12), while
// keeping the proven launch shape (round 11's RT=12 died on LDS/grid shape).
__global__ __launch_bounds__(256) void k_attn(
    const float* __restrict__ f,      // [N][C]
    const float* __restrict__ g,      // [C][N]
    const float4* __restrict__ ut4,   // [N/3][C]
    const float* __restrict__ D0,     // [N]
    const float* __restrict__ D1,     // [N]
    const float* __restrict__ coords, // [N][3]
    const float* __restrict__ sc_w,
    const float* __restrict__ sc_b,
    const float* __restrict__ lin_w,  // [C+3]
    const float* __restrict__ lin_b,
    float* __restrict__ hp,           // [NJC][N][C] partial sums
    float* __restrict__ Mp,           // [N][NJC] partial max
    float* __restrict__ Lp)           // [N][NJC] partial expsum
{
    __shared__ float spart[4][RT][JC];  // 12 KB: per-c-slice score partials
    __shared__ float hpart[4][RT][CC];  // 24 KB: per-wave h partials
    __shared__ float pe[JC][8];         //  4 KB: exp values (6 rows, padded to 8)
    __shared__ float sredm[4][3];
    __shared__ float sreds[4][3];

    const int t    = threadIdx.x;
    const int it   = blockIdx.x & 127;  // row-tile (6 rows = 2 triples)
    const int jc   = blockIdx.x >> 7;   // j-chunk 0..5
    const int i0   = it * RT;
    const int jb   = jc * JC;
    const int w    = t >> 6;
    const int lane = t & 63;

    // u-quads for the 2 row-triples; lane holds c = 64w + lane
    float4 ur0 = ut4[(size_t)(it*2 + 0) * CC + (w << 6) + lane];
    float4 ur1 = ut4[(size_t)(it*2 + 1) * CC + (w << 6) + lane];

    // ---- Phase 1: wave owns c-slice [64w,64w+64); lane owns j-pair jb+2*lane ----
    float2 acc[RT];
    #pragma unroll
    for (int r = 0; r < RT; ++r) acc[r] = make_float2(0.f, 0.f);
    const float2* gq = (const float2*)g + (size_t)(w << 6) * (NN/2) + (jb >> 1) + lane;
    #pragma unroll 8
    for (int cc = 0; cc < 64; ++cc) {
        float2 gv = gq[cc * (NN/2)];   // coalesced 512B/wave, L2-resident
        float w4 = rl(ur0.w, cc);      // VALU-pipe broadcasts, no DS
        float u0 = rl(ur0.x, cc), u1 = rl(ur0.y, cc), u2 = rl(ur0.z, cc);
        float u3 = rl(ur1.x, cc), u4 = rl(ur1.y, cc), u5 = rl(ur1.z, cc);
        acc[0].x = fmaf(w4, fabsf(u0 + gv.x), acc[0].x);
        acc[0].y = fmaf(w4, fabsf(u0 + gv.y), acc[0].y);
        acc[1].x = fmaf(w4, fabsf(u1 + gv.x), acc[1].x);
        acc[1].y = fmaf(w4, fabsf(u1 + gv.y), acc[1].y);
        acc[2].x = fmaf(w4, fabsf(u2 + gv.x), acc[2].x);
        acc[2].y = fmaf(w4, fabsf(u2 + gv.y), acc[2].y);
        acc[3].x = fmaf(w4, fabsf(u3 + gv.x), acc[3].x);
        acc[3].y = fmaf(w4, fabsf(u3 + gv.y), acc[3].y);
        acc[4].x = fmaf(w4, fabsf(u4 + gv.x), acc[4].x);
        acc[4].y = fmaf(w4, fabsf(u4 + gv.y), acc[4].y);
        acc[5].x = fmaf(w4, fabsf(u5 + gv.x), acc[5].x);
        acc[5].y = fmaf(w4, fabsf(u5 + gv.y), acc[5].y);
    }
    #pragma unroll
    for (int r = 0; r < RT; ++r) {
        spart[w][r][2*lane+0] = acc[r].x;
        spart[w][r][2*lane+1] = acc[r].y;
    }
    __syncthreads();

    // ---- Tail: jl = t&127 owns j = jb+jl; half (t>>7) owns rows 3*half..+2 ----
    const int jl   = t & 127;
    const int half = t >> 7;
    const int rb   = 3 * half;
    const int j    = jb + jl;
    float accs[3];
    #pragma unroll
    for (int rr = 0; rr < 3; ++rr)
        accs[rr] = spart[0][rb+rr][jl] + spart[1][rb+rr][jl]
                 + spart[2][rb+rr][jl] + spart[3][rb+rr][jl];

    const float sw0 = sc_w[0], sw1 = sc_w[1], sb = sc_b[0], lb = lin_b[0];
    const float lw30 = lin_w[CC], lw31 = lin_w[CC+1], lw32 = lin_w[CC+2];
    const float cj0 = fmaf(sw1, coords[j*3+0], sb);
    const float cj1 = fmaf(sw1, coords[j*3+1], sb);
    const float cj2 = fmaf(sw1, coords[j*3+2], sb);
    const float d1  = D1[j];
    float scv[3];
    #pragma unroll
    for (int rr = 0; rr < 3; ++rr) {
        const int i = i0 + rb + rr;
        float sd = lw30 * leaky(fmaf(sw0, coords[i*3+0], cj0))
                 + lw31 * leaky(fmaf(sw0, coords[i*3+1], cj1))
                 + lw32 * leaky(fmaf(sw0, coords[i*3+2], cj2));
        scv[rr] = leaky(accs[rr] + sd + 0.6f * (D0[i] + d1) + lb);
    }

    // ---- Phase 2: partial softmax; row rb+rr lives in waves 2*half, 2*half+1 ----
    #pragma unroll
    for (int rr = 0; rr < 3; ++rr) {
        float v = waveMax(scv[rr]);
        if (lane == 0) sredm[w][rr] = v;
    }
    __syncthreads();
    float m[3];
    #pragma unroll
    for (int rr = 0; rr < 3; ++rr)
        m[rr] = fmaxf(sredm[2*half][rr], sredm[2*half+1][rr]);
    float e[3];
    #pragma unroll
    for (int rr = 0; rr < 3; ++rr) {
        e[rr] = __expf(scv[rr] - m[rr]);
        pe[jl][rb + rr] = e[rr];
    }
    #pragma unroll
    for (int rr = 0; rr < 3; ++rr) {
        float v = waveSum(e[rr]);
        if (lane == 0) sreds[w][rr] = v;
    }
    __syncthreads();   // publishes pe + sreds
    if (jl == 0) {     // t==0 (rows 0-2) and t==128 (rows 3-5)
        #pragma unroll
        for (int rr = 0; rr < 3; ++rr) {
            float l = sreds[2*half][rr] + sreds[2*half+1][rr];
            Mp[(i0 + rb + rr) * NJC + jc] = m[rr];
            Lp[(i0 + rb + rr) * NJC + jc] = l;
        }
    }

    // ---- Phase 3: wave w owns j-slice [32w,32w+32); lane owns c-quad 4*lane ----
    float4 h[RT];
    #pragma unroll
    for (int r = 0; r < RT; ++r) h[r] = make_float4(0.f, 0.f, 0.f, 0.f);
    const float4* f4 = (const float4*)f;   // [N][64] float4
    const int jsl = w << 5;
    #pragma unroll 4
    for (int jx = 0; jx < 32; ++jx) {
        const int jl2 = jsl + jx;
        float4 fv = f4[(size_t)(jb + jl2) * 64 + lane];   // coalesced 1KB/wave
        const float4* p4 = (const float4*)&pe[jl2][0];    // wave-uniform b128 x2
        float4 eA = p4[0];
        float4 eB = p4[1];
        fma4(h[0], eA.x, fv); fma4(h[1], eA.y, fv); fma4(h[2], eA.z, fv);
        fma4(h[3], eA.w, fv); fma4(h[4], eB.x, fv); fma4(h[5], eB.y, fv);
    }
    #pragma unroll
    for (int r = 0; r < RT; ++r)
        *(float4*)&hpart[w][r][4*lane] = h[r];
    __syncthreads();

    // ---- Reduce the 4 wave-partials per row; store hp ----
    #pragma unroll
    for (int r = 0; r < RT; ++r) {
        float hh = hpart[0][r][t] + hpart[1][r][t] + hpart[2][r][t] + hpart[3][r][t];
        hp[((size_t)jc * NN + i0 + r) * CC + t] = hh;
    }
}

// Kernel 3: combine the 6 j-chunk partials per row, normalize, elu.
__global__ __launch_bounds__(256) void k_comb(
    const float* __restrict__ hp,
    const float* __restrict__ Mp,
    const float* __restrict__ Lp,
    float* __restrict__ out)
{
    const int t = threadIdx.x;
    const int i = blockIdx.x;

    float mv[NJC];
    #pragma unroll
    for (int k = 0; k < NJC; ++k) mv[k] = Mp[i*NJC + k];
    float M = mv[0];
    #pragma unroll
    for (int k = 1; k < NJC; ++k) M = fmaxf(M, mv[k]);
    float wk[NJC], den = 0.f;
    #pragma unroll
    for (int k = 0; k < NJC; ++k) {
        wk[k] = __expf(mv[k] - M);
        den = fmaf(wk[k], Lp[i*NJC + k], den);
    }
    float inv = 1.0f / den;

    float num = 0.f;
    #pragma unroll
    for (int k = 0; k < NJC; ++k)
        num = fmaf(wk[k], hp[((size_t)k*NN + i)*CC + t], num);
    float v = num * inv;
    out[i*CC + t] = (v > 0.f) ? v : (__expf(v) - 1.0f);
}

extern "C" void kernel_launch(void* const* d_in, const int* in_sizes, int n_in,
                              void* d_out, int out_size, void* d_ws, size_t ws_size,
                              hipStream_t stream) {
    const float* features = (const float*)d_in[0];
    const float* coords   = (const float*)d_in[1];
    // d_in[2] = adj, unused by forward
    const float* FC       = (const float*)d_in[3];
    const float* fc_w     = (const float*)d_in[4];
    const float* fc_b     = (const float*)d_in[5];
    const float* sc_w     = (const float*)d_in[6];
    const float* sc_b     = (const float*)d_in[7];
    const float* lin_w    = (const float*)d_in[8];
    const float* lin_b    = (const float*)d_in[9];
    float* out = (float*)d_out;

    float* f  = (float*)d_ws;              // N*C
    float* g  = f  + NN*CC;                // C*N
    float* D0 = g  + CC*NN;                // N
    float* D1 = D0 + NN;                   // N
    float* Mp = D1 + NN;                   // N*NJC
    float* Lp = Mp + NN*NJC;               // N*NJC
    float* hp = Lp + NN*NJC;               // NJC*N*C
    float4* ut4;
    {
        size_t off = (size_t)((char*)(hp + (size_t)NJC*NN*CC) - (char*)d_ws);
        off = (off + 15) & ~(size_t)15;
        ut4 = (float4*)((char*)d_ws + off); // (N/3)*C float4, 16B-aligned
    }

    k_prep<<<NN/TI, 768, 0, stream>>>(features, FC, fc_w, fc_b, lin_w, f, g, D0, D1, ut4);
    k_attn<<<(NN/RT)*NJC, 256, 0, stream>>>(f, g, ut4, D0, D1, coords, sc_w, sc_b,
                                            lin_w, lin_b, hp, Mp, Lp);
    k_comb<<<NN, 256, 0, stream>>>(hp, Mp, Lp, out);
}